// Round 1
// baseline (2282.269 us; speedup 1.0000x reference)
//
#include <hip/hip_runtime.h>

#define T_TOK 4096
#define HID   2048
#define INTER 2048
#define NEXP  8
#define TK    8192   // T_TOK * TOPK

typedef __bf16 bf16x8 __attribute__((ext_vector_type(8)));
typedef float  f32x4  __attribute__((ext_vector_type(4)));

__device__ __forceinline__ unsigned short f2bf(float f) {
    unsigned u = __builtin_bit_cast(unsigned, f);
    u += 0x7FFFu + ((u >> 16) & 1u);   // RNE; inputs are finite
    return (unsigned short)(u >> 16);
}
__device__ __forceinline__ float bf2f(unsigned short h) {
    unsigned u = ((unsigned)h) << 16;
    return __builtin_bit_cast(float, u);
}

// ---------------- x fp32 -> bf16 ----------------
__global__ void cvt_x_kernel(const float4* __restrict__ src,
                             ushort4* __restrict__ dst, int n4) {
    int i = blockIdx.x * 256 + threadIdx.x;
    if (i < n4) {
        float4 v = src[i];
        ushort4 o;
        o.x = f2bf(v.x); o.y = f2bf(v.y); o.z = f2bf(v.z); o.w = f2bf(v.w);
        dst[i] = o;
    }
}

// ---------------- routing: histogram + prefix + scatter ----------------
__global__ void route_kernel(const int* __restrict__ topk,
                             int* __restrict__ offsets,
                             int* __restrict__ sorted) {
    __shared__ int cnt[NEXP];
    __shared__ int pos[NEXP];
    int tid = threadIdx.x;
    if (tid < NEXP) cnt[tid] = 0;
    __syncthreads();
    for (int i = tid; i < TK; i += 256) atomicAdd(&cnt[topk[i]], 1);
    __syncthreads();
    if (tid == 0) {
        int s = 0;
        for (int e = 0; e < NEXP; e++) { offsets[e] = s; pos[e] = s; s += cnt[e]; }
        offsets[NEXP] = s;   // == TK
    }
    __syncthreads();
    for (int i = tid; i < TK; i += 256) {
        int e = topk[i];
        int p = atomicAdd(&pos[e], 1);
        sorted[p] = i;
    }
}

// ---------------- SwiGLU in-place on ug[8192][4096] (bf16) ----------------
// ug[r, c] = silu(ug[r, c]) * ug[r, 2048 + c], c < 2048
__global__ void swiglu_kernel(unsigned short* __restrict__ ug) {
    int gid = blockIdx.x * 256 + threadIdx.x;      // TK * 512 threads
    int row = gid >> 9;
    int c   = (gid & 511) << 2;
    unsigned short* p = ug + (size_t)row * 4096 + c;
    ushort4 g4 = *(ushort4*)p;
    ushort4 u4 = *(ushort4*)(p + 2048);
    ushort4 o;
    {
        float g, u, s;
        g = bf2f(g4.x); u = bf2f(u4.x); s = g / (1.f + __expf(-g)); o.x = f2bf(s * u);
        g = bf2f(g4.y); u = bf2f(u4.y); s = g / (1.f + __expf(-g)); o.y = f2bf(s * u);
        g = bf2f(g4.z); u = bf2f(u4.z); s = g / (1.f + __expf(-g)); o.z = f2bf(s * u);
        g = bf2f(g4.w); u = bf2f(u4.w); s = g / (1.f + __expf(-g)); o.w = f2bf(s * u);
    }
    *(ushort4*)p = o;
}

// ---------------- grouped GEMM, 128x128 tile, BK=64, mfma 16x16x32 bf16 -----
// MODE 0: A = gathered x_bf16 rows (lda 2048), B = gate_up[e] (N=4096), out ug bf16
// MODE 1: A = ug rows (contiguous in sorted space, lda 4096, first 2048 cols),
//         B = down[e] (N=2048), epilogue: atomicAdd(out[token] , w * val)
template <int MODE>
__global__ __launch_bounds__(256, 2)
void moe_gemm(const unsigned short* __restrict__ A_src,
              const float* __restrict__ W,
              const int* __restrict__ offsets,
              const int* __restrict__ sorted,
              const float* __restrict__ wts,
              unsigned short* __restrict__ ug,
              float* __restrict__ out) {
    constexpr int NTOT = (MODE == 0) ? 4096 : 2048;
    constexpr int KD = 2048;
    constexpr int LDA = (MODE == 0) ? 2048 : 4096;

    const int e   = blockIdx.z;
    const int off = offsets[e];
    const int cnt = offsets[e + 1] - off;
    const int m0  = blockIdx.x * 128;
    if (m0 >= cnt) return;
    const int n0 = blockIdx.y * 128;
    const float* Wb = W + (size_t)e * NTOT * KD;

    // +8 bf16 pad: row stride 72 bf16 = 36 dwords -> bank shift 4/row, no conflicts
    __shared__ unsigned short Asm[128 * 72];
    __shared__ unsigned short Bsm[128 * 72];
    __shared__ int rowid[128];   // MODE0: token id; MODE1: ug row id

    const int tid = threadIdx.x;
    if (tid < 128) {
        int gm = m0 + tid;
        if (MODE == 0) {
            rowid[tid] = (gm < cnt) ? (sorted[off + gm] >> 1) : 0;
        } else {
            if (gm >= cnt) gm = cnt - 1;     // clamp: garbage rows, stores guarded
            rowid[tid] = off + gm;
        }
    }
    __syncthreads();

    const int wave = tid >> 6, lane = tid & 63;
    const int quad = lane >> 4, lrow = lane & 15;
    const int wm = wave >> 1, wn = wave & 1;

    f32x4 acc[4][4];
#pragma unroll
    for (int i = 0; i < 4; i++)
#pragma unroll
        for (int j = 0; j < 4; j++) acc[i][j] = (f32x4){0.f, 0.f, 0.f, 0.f};

    for (int k0 = 0; k0 < KD; k0 += 64) {
        // stage A: 128 x 64 bf16, 1024 chunks of 8 elems (16B)
#pragma unroll
        for (int j = 0; j < 4; j++) {
            int idx = tid + j * 256;
            int r = idx >> 3, c8 = idx & 7;
            const unsigned short* src = A_src + (size_t)rowid[r] * LDA + k0 + c8 * 8;
            uint4 v = *(const uint4*)src;
            *(uint4*)(&Asm[r * 72 + c8 * 8]) = v;
        }
        // stage B: 128 x 64 fp32 -> bf16, 2048 chunks of 4 elems
#pragma unroll
        for (int j = 0; j < 8; j++) {
            int idx = tid + j * 256;
            int r = idx >> 4, c4 = idx & 15;
            const float* src = Wb + (size_t)(n0 + r) * KD + k0 + c4 * 4;
            float4 v = *(const float4*)src;
            ushort4 o;
            o.x = f2bf(v.x); o.y = f2bf(v.y); o.z = f2bf(v.z); o.w = f2bf(v.w);
            *(ushort4*)(&Bsm[r * 72 + c4 * 4]) = o;
        }
        __syncthreads();

#pragma unroll
        for (int ks = 0; ks < 2; ks++) {
            bf16x8 af[4], bfr[4];
#pragma unroll
            for (int mt = 0; mt < 4; mt++)
                af[mt] = *(const bf16x8*)(&Asm[(wm * 64 + mt * 16 + lrow) * 72 + ks * 32 + quad * 8]);
#pragma unroll
            for (int nt = 0; nt < 4; nt++)
                bfr[nt] = *(const bf16x8*)(&Bsm[(wn * 64 + nt * 16 + lrow) * 72 + ks * 32 + quad * 8]);
#pragma unroll
            for (int mt = 0; mt < 4; mt++)
#pragma unroll
                for (int nt = 0; nt < 4; nt++)
                    acc[mt][nt] = __builtin_amdgcn_mfma_f32_16x16x32_bf16(
                        af[mt], bfr[nt], acc[mt][nt], 0, 0, 0);
        }
        __syncthreads();
    }

    // epilogue: C/D layout col = lane&15, row = quad*4 + reg
    if (MODE == 0) {
#pragma unroll
        for (int mt = 0; mt < 4; mt++) {
#pragma unroll
            for (int nt = 0; nt < 4; nt++) {
                int n = n0 + wn * 64 + nt * 16 + lrow;
#pragma unroll
                for (int r = 0; r < 4; r++) {
                    int gm = m0 + wm * 64 + mt * 16 + quad * 4 + r;
                    if (gm < cnt)
                        ug[(size_t)(off + gm) * 4096 + n] = f2bf(acc[mt][nt][r]);
                }
            }
        }
    } else {
#pragma unroll
        for (int mt = 0; mt < 4; mt++) {
#pragma unroll
            for (int r = 0; r < 4; r++) {
                int gm = m0 + wm * 64 + mt * 16 + quad * 4 + r;
                if (gm < cnt) {
                    int idx = sorted[off + gm];
                    float w = wts[idx];
                    float* orow = out + (size_t)(idx >> 1) * HID;
#pragma unroll
                    for (int nt = 0; nt < 4; nt++) {
                        int n = n0 + wn * 64 + nt * 16 + lrow;
                        atomicAdd(orow + n, w * acc[mt][nt][r]);
                    }
                }
            }
        }
    }
}

extern "C" void kernel_launch(void* const* d_in, const int* in_sizes, int n_in,
                              void* d_out, int out_size, void* d_ws, size_t ws_size,
                              hipStream_t stream) {
    const float* x    = (const float*)d_in[0];   // [4096, 2048] fp32
    const int*   topk = (const int*)d_in[1];     // [4096, 2] int32
    const float* wts  = (const float*)d_in[2];   // [4096, 2] fp32
    const float* Wgu  = (const float*)d_in[3];   // [8, 4096, 2048] fp32
    const float* Wd   = (const float*)d_in[4];   // [8, 2048, 2048] fp32
    float* out = (float*)d_out;

    char* ws = (char*)d_ws;
    int* offsets = (int*)ws;                       // 16 ints
    int* sorted  = offsets + 16;                   // 8192 ints
    unsigned short* x_bf = (unsigned short*)(ws + 64 * 1024);                       // 16.8 MB
    unsigned short* ug   = (unsigned short*)(ws + 64 * 1024 + (size_t)T_TOK * HID * 2); // 67.1 MB

    hipMemsetAsync(d_out, 0, (size_t)out_size * sizeof(float), stream);

    cvt_x_kernel<<<(T_TOK * HID / 4) / 256, 256, 0, stream>>>(
        (const float4*)x, (ushort4*)x_bf, T_TOK * HID / 4);

    route_kernel<<<1, 256, 0, stream>>>(topk, offsets, sorted);

    // GEMM1: up_gate = gather(x) @ gate_up[e]^T  -> ug bf16 [8192, 4096]
    moe_gemm<0><<<dim3(64, 32, NEXP), 256, 0, stream>>>(
        x_bf, Wgu, offsets, sorted, wts, ug, nullptr);

    // SwiGLU in place: ug[:, :2048] = silu(gate) * up
    swiglu_kernel<<<(TK * INTER / 4) / 256, 256, 0, stream>>>(ug);

    // GEMM2: out[token] += w * (act @ down[e]^T)
    moe_gemm<1><<<dim3(64, 16, NEXP), 256, 0, stream>>>(
        ug, Wd, offsets, sorted, wts, nullptr, out);
}

// Round 2
// 1492.448 us; speedup vs baseline: 1.5292x; 1.5292x over previous
//
#include <hip/hip_runtime.h>

#define T_TOK 4096
#define HID   2048
#define INTER 2048
#define NEXP  8
#define TK    8192   // T_TOK * TOPK
#define MAXMB 72     // worst-case live m-tiles: 64 + 7, padded

typedef __bf16 bf16x8 __attribute__((ext_vector_type(8)));
typedef float  f32x4  __attribute__((ext_vector_type(4)));

__device__ __forceinline__ unsigned short f2bf(float f) {
    unsigned u = __builtin_bit_cast(unsigned, f);
    u += 0x7FFFu + ((u >> 16) & 1u);   // RNE; inputs are finite
    return (unsigned short)(u >> 16);
}
__device__ __forceinline__ float bf2f(unsigned short h) {
    unsigned u = ((unsigned)h) << 16;
    return __builtin_bit_cast(float, u);
}

// ---------------- x fp32 -> bf16 ----------------
__global__ void cvt_x_kernel(const float4* __restrict__ src,
                             ushort4* __restrict__ dst, int n4) {
    int i = blockIdx.x * 256 + threadIdx.x;
    if (i < n4) {
        float4 v = src[i];
        ushort4 o;
        o.x = f2bf(v.x); o.y = f2bf(v.y); o.z = f2bf(v.z); o.w = f2bf(v.w);
        dst[i] = o;
    }
}

// ------- routing: histogram + prefix + scatter + compact block table -------
__global__ void route_kernel(const int* __restrict__ topk,
                             int* __restrict__ offsets,
                             int* __restrict__ sorted,
                             int* __restrict__ btab,
                             int* __restrict__ nbt) {
    __shared__ int cnt[NEXP];
    __shared__ int pos[NEXP];
    int tid = threadIdx.x;
    if (tid < NEXP) cnt[tid] = 0;
    __syncthreads();
    for (int i = tid; i < TK; i += 256) atomicAdd(&cnt[topk[i]], 1);
    __syncthreads();
    if (tid == 0) {
        int s = 0;
        for (int e = 0; e < NEXP; e++) { offsets[e] = s; pos[e] = s; s += cnt[e]; }
        offsets[NEXP] = s;   // == TK
        // compact table of live (expert, m_tile) pairs — kills null blocks
        int nb = 0;
        for (int e = 0; e < NEXP; e++) {
            int nmb = (cnt[e] + 127) >> 7;
            for (int m = 0; m < nmb; m++) btab[nb++] = (e << 16) | m;
        }
        nbt[0] = nb;   // <= 71
    }
    __syncthreads();
    for (int i = tid; i < TK; i += 256) {
        int e = topk[i];
        int p = atomicAdd(&pos[e], 1);
        sorted[p] = i;
    }
}

// ---------------- SwiGLU in-place on ug[8192][4096] (bf16) ----------------
__global__ void swiglu_kernel(unsigned short* __restrict__ ug) {
    int gid = blockIdx.x * 256 + threadIdx.x;
    int row = gid >> 9;
    int c   = (gid & 511) << 2;
    unsigned short* p = ug + (size_t)row * 4096 + c;
    ushort4 g4 = *(ushort4*)p;
    ushort4 u4 = *(ushort4*)(p + 2048);
    ushort4 o;
    {
        float g, u, s;
        g = bf2f(g4.x); u = bf2f(u4.x); s = g / (1.f + __expf(-g)); o.x = f2bf(s * u);
        g = bf2f(g4.y); u = bf2f(u4.y); s = g / (1.f + __expf(-g)); o.y = f2bf(s * u);
        g = bf2f(g4.z); u = bf2f(u4.z); s = g / (1.f + __expf(-g)); o.z = f2bf(s * u);
        g = bf2f(g4.w); u = bf2f(u4.w); s = g / (1.f + __expf(-g)); o.w = f2bf(s * u);
    }
    *(ushort4*)p = o;
}

// ---------------- grouped GEMM, 128x128 tile, BK=64, mfma 16x16x32 bf16 -----
// Block table drives (expert, m_tile); grid.y = n_tile. No null blocks.
// MODE 0: A = gathered x_bf16 (lda 2048), B = gate_up[e] (N=4096), out ug bf16
// MODE 1: A = ug rows (lda 4096, first 2048 cols), B = down[e] (N=2048),
//         epilogue: atomicAdd(out[token], w * val)
template <int MODE>
__global__ __launch_bounds__(256, 4)
void moe_gemm(const unsigned short* __restrict__ A_src,
              const float* __restrict__ W,
              const int* __restrict__ offsets,
              const int* __restrict__ sorted,
              const float* __restrict__ wts,
              const int* __restrict__ btab,
              const int* __restrict__ nbt,
              unsigned short* __restrict__ ug,
              float* __restrict__ out) {
    constexpr int NTOT = (MODE == 0) ? 4096 : 2048;
    constexpr int KD = 2048;
    constexpr int LDA = (MODE == 0) ? 2048 : 4096;

    const int bx = blockIdx.x;
    if (bx >= nbt[0]) return;            // <=7 stragglers, spread thin
    const int ent = btab[bx];
    const int e   = ent >> 16;
    const int off = offsets[e];
    const int cnt = offsets[e + 1] - off;
    const int m0  = (ent & 0xffff) * 128;
    const int n0 = blockIdx.y * 128;
    const float* Wb = W + (size_t)e * NTOT * KD;

    // +8 bf16 pad: row stride 72 bf16 = 36 dwords -> bank shift 4/row
    __shared__ unsigned short Asm[128 * 72];
    __shared__ unsigned short Bsm[128 * 72];
    __shared__ int rowid[128];   // MODE0: token id; MODE1: ug row id

    const int tid = threadIdx.x;
    if (tid < 128) {
        int gm = m0 + tid;
        if (MODE == 0) {
            rowid[tid] = (gm < cnt) ? (sorted[off + gm] >> 1) : 0;
        } else {
            if (gm >= cnt) gm = cnt - 1;     // clamp: garbage rows, stores guarded
            rowid[tid] = off + gm;
        }
    }
    __syncthreads();

    const int wave = tid >> 6, lane = tid & 63;
    const int quad = lane >> 4, lrow = lane & 15;
    const int wm = wave >> 1, wn = wave & 1;

    // hoist loop-invariant gather pointers (barriers block compiler hoisting)
    const unsigned short* aptr[4];
#pragma unroll
    for (int j = 0; j < 4; j++) {
        int idx = tid + j * 256;
        int r = idx >> 3, c8 = idx & 7;
        aptr[j] = A_src + (size_t)rowid[r] * LDA + c8 * 8;
    }
    const float* bptr[8];
#pragma unroll
    for (int j = 0; j < 8; j++) {
        int idx = tid + j * 256;
        int r = idx >> 4, c4 = idx & 15;
        bptr[j] = Wb + (size_t)(n0 + r) * KD + c4 * 4;
    }

    f32x4 acc[4][4];
#pragma unroll
    for (int i = 0; i < 4; i++)
#pragma unroll
        for (int j = 0; j < 4; j++) acc[i][j] = (f32x4){0.f, 0.f, 0.f, 0.f};

    for (int k0 = 0; k0 < KD; k0 += 64) {
        // stage A: 128 x 64 bf16, 1024 chunks of 8 elems (16B)
#pragma unroll
        for (int j = 0; j < 4; j++) {
            int idx = tid + j * 256;
            int r = idx >> 3, c8 = idx & 7;
            uint4 v = *(const uint4*)(aptr[j] + k0);
            *(uint4*)(&Asm[r * 72 + c8 * 8]) = v;
        }
        // stage B: 128 x 64 fp32 -> bf16, 2048 chunks of 4 elems
#pragma unroll
        for (int j = 0; j < 8; j++) {
            int idx = tid + j * 256;
            int r = idx >> 4, c4 = idx & 15;
            float4 v = *(const float4*)(bptr[j] + k0);
            ushort4 o;
            o.x = f2bf(v.x); o.y = f2bf(v.y); o.z = f2bf(v.z); o.w = f2bf(v.w);
            *(ushort4*)(&Bsm[r * 72 + c4 * 4]) = o;
        }
        __syncthreads();

#pragma unroll
        for (int ks = 0; ks < 2; ks++) {
            bf16x8 af[4], bfr[4];
#pragma unroll
            for (int mt = 0; mt < 4; mt++)
                af[mt] = *(const bf16x8*)(&Asm[(wm * 64 + mt * 16 + lrow) * 72 + ks * 32 + quad * 8]);
#pragma unroll
            for (int nt = 0; nt < 4; nt++)
                bfr[nt] = *(const bf16x8*)(&Bsm[(wn * 64 + nt * 16 + lrow) * 72 + ks * 32 + quad * 8]);
#pragma unroll
            for (int mt = 0; mt < 4; mt++)
#pragma unroll
                for (int nt = 0; nt < 4; nt++)
                    acc[mt][nt] = __builtin_amdgcn_mfma_f32_16x16x32_bf16(
                        af[mt], bfr[nt], acc[mt][nt], 0, 0, 0);
        }
        __syncthreads();
    }

    // epilogue: C/D layout col = lane&15, row = quad*4 + reg
    if (MODE == 0) {
#pragma unroll
        for (int mt = 0; mt < 4; mt++) {
#pragma unroll
            for (int nt = 0; nt < 4; nt++) {
                int n = n0 + wn * 64 + nt * 16 + lrow;
#pragma unroll
                for (int r = 0; r < 4; r++) {
                    int gm = m0 + wm * 64 + mt * 16 + quad * 4 + r;
                    if (gm < cnt)
                        ug[(size_t)(off + gm) * 4096 + n] = f2bf(acc[mt][nt][r]);
                }
            }
        }
    } else {
#pragma unroll
        for (int mt = 0; mt < 4; mt++) {
#pragma unroll
            for (int r = 0; r < 4; r++) {
                int gm = m0 + wm * 64 + mt * 16 + quad * 4 + r;
                if (gm < cnt) {
                    int idx = sorted[off + gm];
                    float w = wts[idx];
                    float* orow = out + (size_t)(idx >> 1) * HID;
#pragma unroll
                    for (int nt = 0; nt < 4; nt++) {
                        int n = n0 + wn * 64 + nt * 16 + lrow;
                        atomicAdd(orow + n, w * acc[mt][nt][r]);
                    }
                }
            }
        }
    }
}

extern "C" void kernel_launch(void* const* d_in, const int* in_sizes, int n_in,
                              void* d_out, int out_size, void* d_ws, size_t ws_size,
                              hipStream_t stream) {
    const float* x    = (const float*)d_in[0];   // [4096, 2048] fp32
    const int*   topk = (const int*)d_in[1];     // [4096, 2] int32
    const float* wts  = (const float*)d_in[2];   // [4096, 2] fp32
    const float* Wgu  = (const float*)d_in[3];   // [8, 4096, 2048] fp32
    const float* Wd   = (const float*)d_in[4];   // [8, 2048, 2048] fp32
    float* out = (float*)d_out;

    char* ws = (char*)d_ws;
    int* offsets = (int*)ws;                       // [0..15]
    int* sorted  = offsets + 16;                   // [16..8207]
    int* btab    = offsets + 8208;                 // [8208..8335]
    int* nbt     = offsets + 8336;                 // [8336]
    unsigned short* x_bf = (unsigned short*)(ws + 64 * 1024);                            // 16.8 MB
    unsigned short* ug   = (unsigned short*)(ws + 64 * 1024 + (size_t)T_TOK * HID * 2);  // 67.1 MB

    hipMemsetAsync(d_out, 0, (size_t)out_size * sizeof(float), stream);

    cvt_x_kernel<<<(T_TOK * HID / 4) / 256, 256, 0, stream>>>(
        (const float4*)x, (ushort4*)x_bf, T_TOK * HID / 4);

    route_kernel<<<1, 256, 0, stream>>>(topk, offsets, sorted, btab, nbt);

    // GEMM1: up_gate = gather(x) @ gate_up[e]^T  -> ug bf16 [8192, 4096]
    moe_gemm<0><<<dim3(MAXMB, 32), 256, 0, stream>>>(
        x_bf, Wgu, offsets, sorted, wts, btab, nbt, ug, nullptr);

    // SwiGLU in place: ug[:, :2048] = silu(gate) * up
    swiglu_kernel<<<(TK * INTER / 4) / 256, 256, 0, stream>>>(ug);

    // GEMM2: out[token] += w * (act @ down[e]^T)
    moe_gemm<1><<<dim3(MAXMB, 16), 256, 0, stream>>>(
        ug, Wd, offsets, sorted, wts, btab, nbt, nullptr, out);
}

// Round 3
// 1107.587 us; speedup vs baseline: 2.0606x; 1.3475x over previous
//
#include <hip/hip_runtime.h>

#define T_TOK 4096
#define HID   2048
#define INTER 2048
#define NEXP  8
#define TK    8192   // T_TOK * TOPK
#define MAXMB 72     // worst-case live m-tiles

typedef __bf16 bf16x8 __attribute__((ext_vector_type(8)));
typedef float  f32x4  __attribute__((ext_vector_type(4)));

__device__ __forceinline__ unsigned short f2bf(float f) {
    unsigned u = __builtin_bit_cast(unsigned, f);
    u += 0x7FFFu + ((u >> 16) & 1u);   // RNE; inputs are finite
    return (unsigned short)(u >> 16);
}

// async global -> LDS, 16B per lane; LDS dest is wave-uniform base + lane*16
__device__ __forceinline__ void gload_lds16(const unsigned short* g, unsigned short* l) {
    __builtin_amdgcn_global_load_lds(
        (const __attribute__((address_space(1))) unsigned int*)g,
        (__attribute__((address_space(3))) unsigned int*)l,
        16, 0, 0);
}

// ---------------- fp32 -> bf16 bulk convert (x and weights) ----------------
__global__ void cvt_kernel(const float4* __restrict__ src,
                           ushort4* __restrict__ dst, int n4) {
    int i = blockIdx.x * 256 + threadIdx.x;
    if (i < n4) {
        float4 v = src[i];
        ushort4 o;
        o.x = f2bf(v.x); o.y = f2bf(v.y); o.z = f2bf(v.z); o.w = f2bf(v.w);
        dst[i] = o;
    }
}

// ------- routing: histogram + prefix + scatter + compact block table -------
__global__ void route_kernel(const int* __restrict__ topk,
                             int* __restrict__ offsets,
                             int* __restrict__ sorted,
                             int* __restrict__ btab,
                             int* __restrict__ nbt) {
    __shared__ int cnt[NEXP];
    __shared__ int pos[NEXP];
    int tid = threadIdx.x;
    if (tid < NEXP) cnt[tid] = 0;
    __syncthreads();
    for (int i = tid; i < TK; i += 256) atomicAdd(&cnt[topk[i]], 1);
    __syncthreads();
    if (tid == 0) {
        int s = 0;
        for (int e = 0; e < NEXP; e++) { offsets[e] = s; pos[e] = s; s += cnt[e]; }
        offsets[NEXP] = s;
        int nb = 0;
        for (int e = 0; e < NEXP; e++) {
            int nmb = (cnt[e] + 127) >> 7;
            for (int m = 0; m < nmb; m++) btab[nb++] = (e << 16) | m;
        }
        nbt[0] = nb;   // <= 71
    }
    __syncthreads();
    for (int i = tid; i < TK; i += 256) {
        int e = topk[i];
        int p = atomicAdd(&pos[e], 1);
        sorted[p] = i;
    }
}

// ---- grouped GEMM, bf16 in/bf16 weights, global_load_lds staging ----------
// LDS tile layout (A and B, 128 rows x 64 cols bf16): 16B chunk at
//   byte addr (k8*128 + row)*16,  k8 = col/8.  This makes the HW's
//   lane-sequential global_load_lds write order == MFMA fragment read order.
// MODE 0 (gate_up + fused SwiGLU): A = gathered x_bf rows; B-tile rows =
//   64 gate rows + 64 up rows of the same 64 output cols; nt 0-1 = gate,
//   nt 2-3 = up, same col -> epilogue silu(g)*u -> act bf16 [TK, 2048].
// MODE 1 (down): A = act rows (contiguous in sorted space); epilogue
//   atomicAdd(out[token], w * val).
template <int MODE>
__global__ __launch_bounds__(256, 3)
void moe_gemm(const unsigned short* __restrict__ A_src,
              const unsigned short* __restrict__ W,   // bf16 weights [e][NW][2048]
              const int* __restrict__ offsets,
              const int* __restrict__ sorted,
              const float* __restrict__ wts,
              const int* __restrict__ btab,
              const int* __restrict__ nbt,
              unsigned short* __restrict__ act,
              float* __restrict__ out) {
    constexpr int KD = 2048;
    constexpr int NW = (MODE == 0) ? 4096 : 2048;

    const int bx = blockIdx.x;
    if (bx >= nbt[0]) return;
    const int ent = btab[bx];
    const int e   = ent >> 16;
    const int off = offsets[e];
    const int cnt = offsets[e + 1] - off;
    const int m0  = (ent & 0xffff) * 128;
    const int n0  = blockIdx.y * ((MODE == 0) ? 64 : 128);
    const unsigned short* Wb = W + (size_t)e * NW * KD;

    __shared__ unsigned short Asm[128 * 64];   // 16 KB
    __shared__ unsigned short Bsm[128 * 64];   // 16 KB
    __shared__ int rowid[128];

    const int tid = threadIdx.x;
    if (tid < 128) {
        int gm = m0 + tid;
        if (MODE == 0) rowid[tid] = (gm < cnt) ? (sorted[off + gm] >> 1) : 0;
        else           rowid[tid] = off + ((gm < cnt) ? gm : (cnt - 1));
    }
    __syncthreads();

    const int wave = tid >> 6, lane = tid & 63;
    const int quad = lane >> 4, lrow = lane & 15;
    const int wm = wave >> 1, wn = wave & 1;
    const int wv1 = wave & 1, wv2 = wave >> 1;

    // ---- staging descriptors (hoisted; only +k0 changes per iter) ----
    // call c: k8 = 2c + wv2, LDS rows wv1*64 + lane
    const int srow = wv1 * 64 + lane;
    const int arid = rowid[srow];
    int wr;
    if (MODE == 0) wr = n0 + wv1 * 32 + (lane & 31) + (lane >> 5) * 2048;
    else           wr = n0 + srow;

    const unsigned short* aptr[4];
    const unsigned short* bptr[4];
    unsigned short* adst[4];
    unsigned short* bdst[4];
#pragma unroll
    for (int c = 0; c < 4; c++) {
        int k8 = 2 * c + wv2;
        aptr[c] = A_src + (size_t)arid * 2048 + k8 * 8;
        bptr[c] = Wb + (size_t)wr * 2048 + k8 * 8;
        adst[c] = &Asm[(k8 * 128 + wv1 * 64) * 8];   // wave-uniform
        bdst[c] = &Bsm[(k8 * 128 + wv1 * 64) * 8];
    }

    const unsigned short* a_rd = &Asm[(quad * 128 + wm * 64 + lrow) * 8];
    const unsigned short* b_rd = &Bsm[(quad * 128 + wn * 64 + lrow) * 8];

    f32x4 acc[4][4];
#pragma unroll
    for (int i = 0; i < 4; i++)
#pragma unroll
        for (int j = 0; j < 4; j++) acc[i][j] = (f32x4){0.f, 0.f, 0.f, 0.f};

    for (int k0 = 0; k0 < KD; k0 += 64) {
#pragma unroll
        for (int c = 0; c < 4; c++) {
            gload_lds16(aptr[c] + k0, adst[c]);
            gload_lds16(bptr[c] + k0, bdst[c]);
        }
        __syncthreads();   // drains vmcnt

#pragma unroll
        for (int ks = 0; ks < 2; ks++) {
            bf16x8 af[4], bfr[4];
#pragma unroll
            for (int mt = 0; mt < 4; mt++)
                af[mt] = *(const bf16x8*)(a_rd + ks * 4096 + mt * 128);
#pragma unroll
            for (int nt = 0; nt < 4; nt++)
                bfr[nt] = *(const bf16x8*)(b_rd + ks * 4096 + nt * 128);
#pragma unroll
            for (int mt = 0; mt < 4; mt++)
#pragma unroll
                for (int nt = 0; nt < 4; nt++)
                    acc[mt][nt] = __builtin_amdgcn_mfma_f32_16x16x32_bf16(
                        af[mt], bfr[nt], acc[mt][nt], 0, 0, 0);
        }
        __syncthreads();
    }

    // epilogue: C/D layout col = lane&15 (lrow), row = quad*4 + reg
    if (MODE == 0) {
#pragma unroll
        for (int mt = 0; mt < 4; mt++) {
#pragma unroll
            for (int r = 0; r < 4; r++) {
                int gm = m0 + wm * 64 + mt * 16 + quad * 4 + r;
                if (gm < cnt) {
                    unsigned short* arow = act + (size_t)(off + gm) * 2048;
#pragma unroll
                    for (int nt = 0; nt < 2; nt++) {
                        int col = n0 + wn * 32 + nt * 16 + lrow;
                        float g = acc[mt][nt][r];
                        float u = acc[mt][nt + 2][r];
                        float s = g / (1.f + __expf(-g));
                        arow[col] = f2bf(s * u);
                    }
                }
            }
        }
    } else {
#pragma unroll
        for (int mt = 0; mt < 4; mt++) {
#pragma unroll
            for (int r = 0; r < 4; r++) {
                int gm = m0 + wm * 64 + mt * 16 + quad * 4 + r;
                if (gm < cnt) {
                    int idx = sorted[off + gm];
                    float w = wts[idx];
                    float* orow = out + (size_t)(idx >> 1) * HID;
#pragma unroll
                    for (int nt = 0; nt < 4; nt++) {
                        int n = n0 + wn * 64 + nt * 16 + lrow;
                        atomicAdd(orow + n, w * acc[mt][nt][r]);
                    }
                }
            }
        }
    }
}

extern "C" void kernel_launch(void* const* d_in, const int* in_sizes, int n_in,
                              void* d_out, int out_size, void* d_ws, size_t ws_size,
                              hipStream_t stream) {
    const float* x    = (const float*)d_in[0];   // [4096, 2048] fp32
    const int*   topk = (const int*)d_in[1];     // [4096, 2] int32
    const float* wts  = (const float*)d_in[2];   // [4096, 2] fp32
    const float* Wgu  = (const float*)d_in[3];   // [8, 4096, 2048] fp32
    const float* Wd   = (const float*)d_in[4];   // [8, 2048, 2048] fp32
    float* out = (float*)d_out;

    // ws layout (Wd_bf aliases Wgu_bf: converted after GEMM1, stream-serial):
    //   [0, 64K)            tables
    //   [64K, +134.2M)      Wgu_bf  (later overwritten by Wd_bf, 67.1M)
    //   [+, +16.8M)         x_bf
    //   [+, +33.6M)         act     -> total ~184.7 MB
    char* ws = (char*)d_ws;
    int* offsets = (int*)ws;
    int* sorted  = offsets + 16;
    int* btab    = offsets + 8208;
    int* nbt     = offsets + 8336;
    unsigned short* Wgu_bf = (unsigned short*)(ws + 65536);
    unsigned short* Wd_bf  = Wgu_bf;   // alias, written after GEMM1
    unsigned short* x_bf   = (unsigned short*)(ws + 65536 + (size_t)NEXP * 2 * INTER * HID * 2);
    unsigned short* act    = x_bf + (size_t)T_TOK * HID;

    hipMemsetAsync(d_out, 0, (size_t)out_size * sizeof(float), stream);

    cvt_kernel<<<(T_TOK * HID / 4) / 256, 256, 0, stream>>>(
        (const float4*)x, (ushort4*)x_bf, T_TOK * HID / 4);
    cvt_kernel<<<(NEXP * 2 * INTER * HID / 4) / 256, 256, 0, stream>>>(
        (const float4*)Wgu, (ushort4*)Wgu_bf, NEXP * 2 * INTER * HID / 4);

    route_kernel<<<1, 256, 0, stream>>>(topk, offsets, sorted, btab, nbt);

    // GEMM1 + fused SwiGLU: act = silu(x@gate^T) * (x@up^T), bf16 [TK, 2048]
    moe_gemm<0><<<dim3(MAXMB, 32), 256, 0, stream>>>(
        x_bf, Wgu_bf, offsets, sorted, wts, btab, nbt, act, nullptr);

    cvt_kernel<<<(NEXP * HID * INTER / 4) / 256, 256, 0, stream>>>(
        (const float4*)Wd, (ushort4*)Wd_bf, NEXP * HID * INTER / 4);

    // GEMM2: out[token] += w * (act @ down[e]^T)
    moe_gemm<1><<<dim3(MAXMB, 16), 256, 0, stream>>>(
        act, Wd_bf, offsets, sorted, wts, btab, nbt, nullptr, out);
}